// Round 1
// baseline (2219.332 us; speedup 1.0000x reference)
//
#include <hip/hip_runtime.h>
#include <math.h>

#define B_      16
#define NPUS    1024
#define MEMS    4096
#define INS     512
#define RS      256
#define MD      128
#define GRUIN   640
#define MMUO    644
#define NROWS   (B_*NPUS)   // 16384

// d_out flat offsets (reference return order)
#define O_OUT   0u
#define O_REGS  8388608u
#define O_WKEY  12582912u
#define O_WVAL  14680064u
#define O_WGATE 16777216u
#define O_SSDK  16793600u
#define O_SSDV  18890752u
#define O_SSDG  20987904u

__device__ __forceinline__ float sigf(float x){ return 1.f/(1.f+expf(-x)); }

// ---------------- K1: MMU GEMM  C[16384,644] = regs[16384,256] * Wmmu[644,256]^T + b ----------------
__global__ __launch_bounds__(256) void k_mmu(const float* __restrict__ A,
                                             const float* __restrict__ W,
                                             const float* __restrict__ bias,
                                             float* __restrict__ out,
                                             float* __restrict__ query)
{
    const int BK = 32;
    __shared__ float As[BK][64+1];
    __shared__ float Ws[BK][64+1];
    const int t = threadIdx.x;
    const int m0 = blockIdx.x * 64;
    const int n0 = blockIdx.y * 64;
    const int ty = t >> 4, tx = t & 15;
    float acc[4][4] = {};
    for (int k0 = 0; k0 < RS; k0 += BK) {
        #pragma unroll
        for (int i = 0; i < 8; i++) {
            int l = t + i*256; int m = l >> 5, k = l & 31;
            As[k][m] = A[(size_t)(m0+m)*RS + k0 + k];
        }
        #pragma unroll
        for (int i = 0; i < 8; i++) {
            int l = t + i*256; int n = l >> 5, k = l & 31;
            int gn = n0 + n;
            Ws[k][n] = (gn < MMUO) ? W[(size_t)gn*RS + k0 + k] : 0.f;
        }
        __syncthreads();
        #pragma unroll
        for (int k = 0; k < BK; k++) {
            float a[4], b[4];
            #pragma unroll
            for (int i = 0; i < 4; i++) a[i] = As[k][ty*4+i];
            #pragma unroll
            for (int j = 0; j < 4; j++) b[j] = Ws[k][tx*4+j];
            #pragma unroll
            for (int i = 0; i < 4; i++)
                #pragma unroll
                for (int j = 0; j < 4; j++) acc[i][j] += a[i]*b[j];
        }
        __syncthreads();
    }
    #pragma unroll
    for (int i = 0; i < 4; i++) {
        int r = m0 + ty*4 + i;
        #pragma unroll
        for (int j = 0; j < 4; j++) {
            int o = n0 + tx*4 + j;
            if (o >= MMUO) continue;
            float v = acc[i][j] + bias[o];
            if      (o < MD)        query[(size_t)r*MD + o] = v;
            else if (o < 2*MD)      out[O_WKEY + (size_t)r*MD + (o -   MD)] = v;
            else if (o < 3*MD)      out[O_WVAL + (size_t)r*MD + (o - 2*MD)] = v;
            else if (o == 3*MD)     out[O_WGATE + r] = sigf(v);
            else if (o < 4*MD + 1)  out[O_SSDK + (size_t)r*MD + (o - (3*MD+1))] = v;
            else if (o < 5*MD + 1)  out[O_SSDV + (size_t)r*MD + (o - (4*MD+1))] = v;
            else                    out[O_SSDG + (size_t)r*3  + (o - (5*MD+1))] = v; // raw logit
        }
    }
}

// ---------------- K1b: softmax over the 3 ssd_gate logits ----------------
__global__ void k_softmax3(float* __restrict__ out)
{
    int r = blockIdx.x*256 + threadIdx.x;
    if (r >= NROWS) return;
    float* p = out + O_SSDG + (size_t)r*3;
    float a = p[0], b = p[1], c = p[2];
    float m = fmaxf(a, fmaxf(b, c));
    float ea = expf(a-m), eb = expf(b-m), ec = expf(c-m);
    float inv = 1.f/(ea+eb+ec);
    p[0] = ea*inv; p[1] = eb*inv; p[2] = ec*inv;
}

// ---------------- K2: flash attention  rd[16384,128] ----------------
// block = 256 thr, handles 64 queries of one batch; loops memory in 32-row tiles.
__global__ __launch_bounds__(256) void k_attn(const float* __restrict__ query,
                                              const float* __restrict__ mem,
                                              float* __restrict__ rd)
{
    __shared__ float Qs[64][MD+1];
    __shared__ float Ms[32][MD+1];
    __shared__ float Ss[64][33];
    const int t = threadIdx.x;
    const int b  = blockIdx.x >> 4;
    const int qt = blockIdx.x & 15;
    const int qbase = b*NPUS + qt*64;

    for (int l = t; l < 64*32; l += 256) {          // Q tile: 2048 float4
        int row = l >> 5, c4 = l & 31;
        const float4 v = ((const float4*)query)[(size_t)(qbase+row)*32 + c4];
        Qs[row][c4*4+0]=v.x; Qs[row][c4*4+1]=v.y; Qs[row][c4*4+2]=v.z; Qs[row][c4*4+3]=v.w;
    }

    float m_run = -INFINITY, l_run = 0.f;
    float O[32];
    #pragma unroll
    for (int i = 0; i < 32; i++) O[i] = 0.f;
    const int q_own = t >> 2, g = t & 3;   // softmax/PV mapping: 4 threads per query
    const int tq = t >> 4, tm = t & 15;    // score-GEMM mapping: 4q x 2m micro
    const float scale = 0.08838834764831845f;  // 1/sqrt(128)

    for (int mt = 0; mt < MEMS; mt += 32) {
        __syncthreads();   // prev phase C done before Ms/Ss overwritten
        for (int l = t; l < 32*32; l += 256) {      // mem tile: 1024 float4
            int row = l >> 5, c4 = l & 31;
            const float4 v = ((const float4*)mem)[((size_t)b*MEMS + mt + row)*32 + c4];
            Ms[row][c4*4+0]=v.x; Ms[row][c4*4+1]=v.y; Ms[row][c4*4+2]=v.z; Ms[row][c4*4+3]=v.w;
        }
        __syncthreads();
        // phase A: scores 64x32, micro 4x2
        float acc[4][2] = {};
        for (int k = 0; k < MD; k++) {
            float a0=Qs[tq*4+0][k], a1=Qs[tq*4+1][k], a2=Qs[tq*4+2][k], a3=Qs[tq*4+3][k];
            float b0=Ms[tm*2+0][k], b1=Ms[tm*2+1][k];
            acc[0][0]+=a0*b0; acc[0][1]+=a0*b1;
            acc[1][0]+=a1*b0; acc[1][1]+=a1*b1;
            acc[2][0]+=a2*b0; acc[2][1]+=a2*b1;
            acc[3][0]+=a3*b0; acc[3][1]+=a3*b1;
        }
        #pragma unroll
        for (int i = 0; i < 4; i++) {
            Ss[tq*4+i][tm*2+0] = acc[i][0]*scale;
            Ss[tq*4+i][tm*2+1] = acc[i][1]*scale;
        }
        __syncthreads();
        // phase B: online softmax update (thread handles q_own, cols g*8..g*8+7)
        float tmax = -INFINITY;
        #pragma unroll
        for (int j = 0; j < 8; j++) tmax = fmaxf(tmax, Ss[q_own][g*8+j]);
        tmax = fmaxf(tmax, __shfl_xor(tmax, 1, 4));
        tmax = fmaxf(tmax, __shfl_xor(tmax, 2, 4));
        float m_new = fmaxf(m_run, tmax);
        float alpha = expf(m_run - m_new);
        float psum = 0.f;
        #pragma unroll
        for (int j = 0; j < 8; j++) {
            float p = expf(Ss[q_own][g*8+j] - m_new);
            Ss[q_own][g*8+j] = p; psum += p;
        }
        psum += __shfl_xor(psum, 1, 4);
        psum += __shfl_xor(psum, 2, 4);
        l_run = l_run*alpha + psum;
        m_run = m_new;
        #pragma unroll
        for (int i = 0; i < 32; i++) O[i] *= alpha;
        __syncthreads();
        // phase C: PV — thread owns (q_own, dims g+4*i), strided d to avoid bank conflicts
        for (int j = 0; j < 32; j++) {
            float p = Ss[q_own][j];
            #pragma unroll
            for (int i = 0; i < 32; i++) O[i] += p * Ms[j][g + 4*i];
        }
    }
    float inv = 1.f/l_run;
    int r = qbase + q_own;
    #pragma unroll
    for (int i = 0; i < 32; i++) rd[(size_t)r*MD + g + 4*i] = O[i]*inv;
}

// ---------------- K3: fused GRU. Block tile 64 rows x 32 gate-cols, 4 accs per (r,c) ----------------
__global__ __launch_bounds__(256) void k_gru(const float* __restrict__ inp,
                                             const float* __restrict__ rd,
                                             const float* __restrict__ regs,
                                             const float* __restrict__ Wih,
                                             const float* __restrict__ bih,
                                             const float* __restrict__ Whh,
                                             const float* __restrict__ bhh,
                                             float* __restrict__ newregs)
{
    const int BK = 32;
    __shared__ float As[BK][64+1];
    __shared__ float Ws[3][BK][32+1];
    const int t = threadIdx.x;
    const int m0 = blockIdx.x * 64;
    const int n0 = blockIdx.y * 32;
    const int ty = t >> 4, tx = t & 15;     // rows 4*ty.., cols 2*tx..
    float aR[4][2]={}, aZ[4][2]={}, aNi[4][2]={}, aNh[4][2]={};

    // phase 1: x=[inp | rd] (K=640) vs W_ih
    for (int k0 = 0; k0 < GRUIN; k0 += BK) {
        #pragma unroll
        for (int i = 0; i < 8; i++) {
            int l = t + i*256; int m = l >> 5, k = l & 31;
            int gk = k0 + k; int r = m0 + m;
            float v = (gk < INS) ? inp[(size_t)(r >> 10)*INS + gk]
                                 : rd[(size_t)r*MD + (gk - INS)];
            As[k][m] = v;
        }
        #pragma unroll
        for (int i = 0; i < 12; i++) {
            int l = t + i*256; int gg = l >> 10; int rem = l & 1023;
            int n = rem >> 5, k = rem & 31;
            Ws[gg][k][n] = Wih[(size_t)(gg*RS + n0 + n)*GRUIN + k0 + k];
        }
        __syncthreads();
        #pragma unroll
        for (int k = 0; k < BK; k++) {
            float a[4];
            #pragma unroll
            for (int i = 0; i < 4; i++) a[i] = As[k][ty*4+i];
            float bR[2], bZ[2], bN[2];
            #pragma unroll
            for (int j = 0; j < 2; j++) {
                bR[j]=Ws[0][k][tx*2+j]; bZ[j]=Ws[1][k][tx*2+j]; bN[j]=Ws[2][k][tx*2+j];
            }
            #pragma unroll
            for (int i = 0; i < 4; i++)
                #pragma unroll
                for (int j = 0; j < 2; j++) {
                    aR[i][j]  += a[i]*bR[j];
                    aZ[i][j]  += a[i]*bZ[j];
                    aNi[i][j] += a[i]*bN[j];
                }
        }
        __syncthreads();
    }
    // phase 2: curr (K=256) vs W_hh
    for (int k0 = 0; k0 < RS; k0 += BK) {
        #pragma unroll
        for (int i = 0; i < 8; i++) {
            int l = t + i*256; int m = l >> 5, k = l & 31;
            As[k][m] = regs[(size_t)(m0+m)*RS + k0 + k];
        }
        #pragma unroll
        for (int i = 0; i < 12; i++) {
            int l = t + i*256; int gg = l >> 10; int rem = l & 1023;
            int n = rem >> 5, k = rem & 31;
            Ws[gg][k][n] = Whh[(size_t)(gg*RS + n0 + n)*RS + k0 + k];
        }
        __syncthreads();
        #pragma unroll
        for (int k = 0; k < BK; k++) {
            float a[4];
            #pragma unroll
            for (int i = 0; i < 4; i++) a[i] = As[k][ty*4+i];
            float bR[2], bZ[2], bN[2];
            #pragma unroll
            for (int j = 0; j < 2; j++) {
                bR[j]=Ws[0][k][tx*2+j]; bZ[j]=Ws[1][k][tx*2+j]; bN[j]=Ws[2][k][tx*2+j];
            }
            #pragma unroll
            for (int i = 0; i < 4; i++)
                #pragma unroll
                for (int j = 0; j < 2; j++) {
                    aR[i][j]  += a[i]*bR[j];
                    aZ[i][j]  += a[i]*bZ[j];
                    aNh[i][j] += a[i]*bN[j];
                }
        }
        __syncthreads();
    }
    // epilogue: gates
    #pragma unroll
    for (int i = 0; i < 4; i++) {
        int r = m0 + ty*4 + i;
        #pragma unroll
        for (int j = 0; j < 2; j++) {
            int o = n0 + tx*2 + j;
            float rr = sigf(aR[i][j] + bih[o]        + bhh[o]);
            float zz = sigf(aZ[i][j] + bih[o + RS]   + bhh[o + RS]);
            float nn = tanhf(aNi[i][j] + bih[o + 2*RS] + rr*(aNh[i][j] + bhh[o + 2*RS]));
            float cv = regs[(size_t)r*RS + o];
            newregs[(size_t)r*RS + o] = (1.f - zz)*nn + zz*cv;
        }
    }
}

// ---------------- K4: output GEMM  out0[16384,512] = newregs * Wout[512,256]^T + b ----------------
__global__ __launch_bounds__(256) void k_out(const float* __restrict__ A,
                                             const float* __restrict__ W,
                                             const float* __restrict__ bias,
                                             float* __restrict__ out0)
{
    const int BK = 32;
    __shared__ float As[BK][64+1];
    __shared__ float Ws[BK][64+1];
    const int t = threadIdx.x;
    const int m0 = blockIdx.x * 64;
    const int n0 = blockIdx.y * 64;
    const int ty = t >> 4, tx = t & 15;
    float acc[4][4] = {};
    for (int k0 = 0; k0 < RS; k0 += BK) {
        #pragma unroll
        for (int i = 0; i < 8; i++) {
            int l = t + i*256; int m = l >> 5, k = l & 31;
            As[k][m] = A[(size_t)(m0+m)*RS + k0 + k];
        }
        #pragma unroll
        for (int i = 0; i < 8; i++) {
            int l = t + i*256; int n = l >> 5, k = l & 31;
            Ws[k][n] = W[(size_t)(n0+n)*RS + k0 + k];
        }
        __syncthreads();
        #pragma unroll
        for (int k = 0; k < BK; k++) {
            float a[4], b[4];
            #pragma unroll
            for (int i = 0; i < 4; i++) a[i] = As[k][ty*4+i];
            #pragma unroll
            for (int j = 0; j < 4; j++) b[j] = Ws[k][tx*4+j];
            #pragma unroll
            for (int i = 0; i < 4; i++)
                #pragma unroll
                for (int j = 0; j < 4; j++) acc[i][j] += a[i]*b[j];
        }
        __syncthreads();
    }
    #pragma unroll
    for (int i = 0; i < 4; i++) {
        int r = m0 + ty*4 + i;
        #pragma unroll
        for (int j = 0; j < 4; j++) {
            int o = n0 + tx*4 + j;
            out0[(size_t)r*INS + o] = acc[i][j] + bias[o];
        }
    }
}

extern "C" void kernel_launch(void* const* d_in, const int* in_sizes, int n_in,
                              void* d_out, int out_size, void* d_ws, size_t ws_size,
                              hipStream_t stream)
{
    const float* inp  = (const float*)d_in[0];
    const float* regs = (const float*)d_in[1];
    const float* mem  = (const float*)d_in[2];
    const float* Wih  = (const float*)d_in[3];
    const float* bih  = (const float*)d_in[4];
    const float* Whh  = (const float*)d_in[5];
    const float* bhh  = (const float*)d_in[6];
    const float* Wmmu = (const float*)d_in[7];
    const float* bmmu = (const float*)d_in[8];
    const float* Wout = (const float*)d_in[9];
    const float* bout = (const float*)d_in[10];
    float* out = (float*)d_out;

    float* query = (float*)d_ws;                       //  16384*128 f32 =  8 MB
    float* rd    = query + (size_t)NROWS*MD;           //  16384*128 f32 =  8 MB

    dim3 g1(NROWS/64, (MMUO + 63)/64);                 // 256 x 11
    k_mmu<<<g1, 256, 0, stream>>>(regs, Wmmu, bmmu, out, query);
    k_softmax3<<<NROWS/256, 256, 0, stream>>>(out);
    k_attn<<<B_*16, 256, 0, stream>>>(query, mem, rd); // 256 blocks
    dim3 g3(NROWS/64, RS/32);                          // 256 x 8
    k_gru<<<g3, 256, 0, stream>>>(inp, rd, regs, Wih, bih, Whh, bhh, out + O_REGS);
    dim3 g4(NROWS/64, INS/64);                         // 256 x 8
    k_out<<<g4, 256, 0, stream>>>(out + O_REGS, Wout, bout, out);
}

// Round 2
// 1388.489 us; speedup vs baseline: 1.5984x; 1.5984x over previous
//
#include <hip/hip_runtime.h>
#include <hip/hip_bf16.h>
#include <math.h>

#define B_      16
#define NPUS    1024
#define MEMS    4096
#define INS     512
#define RS      256
#define MD      128
#define GRUIN   640
#define MMUO    644
#define NROWS   (B_*NPUS)   // 16384

// d_out flat offsets (reference return order)
#define O_OUT   0u
#define O_REGS  8388608u
#define O_WKEY  12582912u
#define O_WVAL  14680064u
#define O_WGATE 16777216u
#define O_SSDK  16793600u
#define O_SSDV  18890752u
#define O_SSDG  20987904u

typedef __attribute__((ext_vector_type(8))) short bf16x8;
typedef __attribute__((ext_vector_type(4))) float f32x4;

__device__ __forceinline__ float sigf(float x){ return 1.f/(1.f+expf(-x)); }

// ---------------- K0: convert memory_context to bf16, row-major + transposed ----------------
// memB[b][m][d] bf16 ; memT[b][d][m] bf16
__global__ __launch_bounds__(256) void k_conv(const float* __restrict__ mem,
                                              __hip_bfloat16* __restrict__ memB,
                                              __hip_bfloat16* __restrict__ memT)
{
    __shared__ float Ms[32][129];
    const int t = threadIdx.x;
    const int b = blockIdx.x >> 7;            // 128 m-tiles per batch
    const int m0 = (blockIdx.x & 127) << 5;   // 32 rows per tile
    const float* src = mem + ((size_t)b*MEMS + m0)*MD;
    for (int idx = t; idx < 32*128; idx += 256) {
        int m = idx >> 7, d = idx & 127;
        float v = src[(size_t)m*MD + d];
        Ms[m][d] = v;
        memB[((size_t)b*MEMS + m0 + m)*MD + d] = __float2bfloat16(v);
    }
    __syncthreads();
    for (int idx = t; idx < 128*32; idx += 256) {
        int d = idx >> 5, m = idx & 31;
        memT[((size_t)b*MD + d)*MEMS + m0 + m] = __float2bfloat16(Ms[m][d]);
    }
}

// ---------------- K1: MMU GEMM  C[16384,644] = regs[16384,256] * Wmmu[644,256]^T + b ----------------
__global__ __launch_bounds__(256) void k_mmu(const float* __restrict__ A,
                                             const float* __restrict__ W,
                                             const float* __restrict__ bias,
                                             float* __restrict__ out,
                                             __hip_bfloat16* __restrict__ qbf)
{
    const int BK = 32;
    __shared__ float As[BK][64+1];
    __shared__ float Ws[BK][64+1];
    const int t = threadIdx.x;
    const int m0 = blockIdx.x * 64;
    const int n0 = blockIdx.y * 64;
    const int ty = t >> 4, tx = t & 15;
    float acc[4][4] = {};
    for (int k0 = 0; k0 < RS; k0 += BK) {
        #pragma unroll
        for (int i = 0; i < 8; i++) {
            int l = t + i*256; int m = l >> 5, k = l & 31;
            As[k][m] = A[(size_t)(m0+m)*RS + k0 + k];
        }
        #pragma unroll
        for (int i = 0; i < 8; i++) {
            int l = t + i*256; int n = l >> 5, k = l & 31;
            int gn = n0 + n;
            Ws[k][n] = (gn < MMUO) ? W[(size_t)gn*RS + k0 + k] : 0.f;
        }
        __syncthreads();
        #pragma unroll
        for (int k = 0; k < BK; k++) {
            float a[4], b[4];
            #pragma unroll
            for (int i = 0; i < 4; i++) a[i] = As[k][ty*4+i];
            #pragma unroll
            for (int j = 0; j < 4; j++) b[j] = Ws[k][tx*4+j];
            #pragma unroll
            for (int i = 0; i < 4; i++)
                #pragma unroll
                for (int j = 0; j < 4; j++) acc[i][j] += a[i]*b[j];
        }
        __syncthreads();
    }
    #pragma unroll
    for (int i = 0; i < 4; i++) {
        int r = m0 + ty*4 + i;
        #pragma unroll
        for (int j = 0; j < 4; j++) {
            int o = n0 + tx*4 + j;
            if (o >= MMUO) continue;
            float v = acc[i][j] + bias[o];
            if      (o < MD)        qbf[(size_t)r*MD + o] = __float2bfloat16(v * 0.08838834764831845f);
            else if (o < 2*MD)      out[O_WKEY + (size_t)r*MD + (o -   MD)] = v;
            else if (o < 3*MD)      out[O_WVAL + (size_t)r*MD + (o - 2*MD)] = v;
            else if (o == 3*MD)     out[O_WGATE + r] = sigf(v);
            else if (o < 4*MD + 1)  out[O_SSDK + (size_t)r*MD + (o - (3*MD+1))] = v;
            else if (o < 5*MD + 1)  out[O_SSDV + (size_t)r*MD + (o - (4*MD+1))] = v;
            else                    out[O_SSDG + (size_t)r*3  + (o - (5*MD+1))] = v; // raw logit
        }
    }
}

// ---------------- K1b: softmax over the 3 ssd_gate logits ----------------
__global__ void k_softmax3(float* __restrict__ out)
{
    int r = blockIdx.x*256 + threadIdx.x;
    if (r >= NROWS) return;
    float* p = out + O_SSDG + (size_t)r*3;
    float a = p[0], b = p[1], c = p[2];
    float m = fmaxf(a, fmaxf(b, c));
    float ea = expf(a-m), eb = expf(b-m), ec = expf(c-m);
    float inv = 1.f/(ea+eb+ec);
    p[0] = ea*inv; p[1] = eb*inv; p[2] = ec*inv;
}

// ---------------- K2: MFMA flash attention  rd[16384,128] ----------------
// 256 thr = 4 waves; wave w owns 16 q-rows. No K/V LDS staging (L2-resident, 1MB/batch).
// Q pre-scaled bf16 in registers. P via per-wave LDS (layout shuffle C->A frag).
__global__ __launch_bounds__(256) void k_attn(const __hip_bfloat16* __restrict__ qb,
                                              const __hip_bfloat16* __restrict__ memB,
                                              const __hip_bfloat16* __restrict__ memT,
                                              float* __restrict__ rd)
{
    __shared__ __hip_bfloat16 Pl[4][16][40];   // per-wave P tile, 80B rows (16B-aligned)
    const int t  = threadIdx.x;
    const int w  = t >> 6, l = t & 63;
    const int lg = l >> 4, ll = l & 15;
    const int b  = blockIdx.x >> 4;
    const int qt = blockIdx.x & 15;
    const int qrow0 = (b << 10) + (qt << 6) + (w << 4);   // wave's first q row

    // Q A-fragments: lane ll -> q-row, lane group lg -> d-slice
    bf16x8 qf[4];
    {
        const short* qp = (const short*)qb + (size_t)(qrow0 + ll)*MD;
        #pragma unroll
        for (int ks = 0; ks < 4; ks++)
            qf[ks] = *(const bf16x8*)(qp + ks*32 + lg*8);
    }
    f32x4 O[8];
    #pragma unroll
    for (int dt = 0; dt < 8; dt++) O[dt] = (f32x4){0.f,0.f,0.f,0.f};
    float m_run[4], l_run[4];
    #pragma unroll
    for (int r = 0; r < 4; r++) { m_run[r] = -INFINITY; l_run[r] = 0.f; }

    const short* Mb = (const short*)memB + (size_t)b*MEMS*MD;
    const short* Mt = (const short*)memT + (size_t)b*MD*MEMS;

    for (int k0 = 0; k0 < MEMS; k0 += 32) {
        // ---- QK^T: S[16q][32k] ----
        f32x4 s0 = (f32x4){0,0,0,0}, s1 = (f32x4){0,0,0,0};
        #pragma unroll
        for (int ks = 0; ks < 4; ks++) {
            bf16x8 b0 = *(const bf16x8*)(Mb + (size_t)(k0      + ll)*MD + ks*32 + lg*8);
            bf16x8 b1 = *(const bf16x8*)(Mb + (size_t)(k0 + 16 + ll)*MD + ks*32 + lg*8);
            s0 = __builtin_amdgcn_mfma_f32_16x16x32_bf16(qf[ks], b0, s0, 0, 0, 0);
            s1 = __builtin_amdgcn_mfma_f32_16x16x32_bf16(qf[ks], b1, s1, 0, 0, 0);
        }
        // ---- online softmax (C layout: col=ll=key, row=lg*4+r=query) ----
        float alpha[4];
        #pragma unroll
        for (int r = 0; r < 4; r++) {
            float v = fmaxf(s0[r], s1[r]);
            v = fmaxf(v, __shfl_xor(v, 1));
            v = fmaxf(v, __shfl_xor(v, 2));
            v = fmaxf(v, __shfl_xor(v, 4));
            v = fmaxf(v, __shfl_xor(v, 8));
            float mnew = fmaxf(m_run[r], v);
            alpha[r] = __expf(m_run[r] - mnew);
            m_run[r] = mnew;
            float p0 = __expf(s0[r] - mnew);
            float p1 = __expf(s1[r] - mnew);
            Pl[w][lg*4 + r][ll]      = __float2bfloat16(p0);
            Pl[w][lg*4 + r][16 + ll] = __float2bfloat16(p1);
            float p = p0 + p1;
            p += __shfl_xor(p, 1);
            p += __shfl_xor(p, 2);
            p += __shfl_xor(p, 4);
            p += __shfl_xor(p, 8);
            l_run[r] = l_run[r]*alpha[r] + p;
        }
        #pragma unroll
        for (int dt = 0; dt < 8; dt++) {
            #pragma unroll
            for (int r = 0; r < 4; r++) O[dt][r] *= alpha[r];
        }
        // ---- PV: O[16q][128d] += P[16q][32k] * M[32k][128d] ----
        __builtin_amdgcn_wave_barrier();
        bf16x8 pa = *(const bf16x8*)(&Pl[w][ll][lg*8]);   // A-frag of P
        __builtin_amdgcn_wave_barrier();
        #pragma unroll
        for (int dt = 0; dt < 8; dt++) {
            bf16x8 vb = *(const bf16x8*)(Mt + (size_t)(dt*16 + ll)*MEMS + k0 + lg*8);
            O[dt] = __builtin_amdgcn_mfma_f32_16x16x32_bf16(pa, vb, O[dt], 0, 0, 0);
        }
    }
    #pragma unroll
    for (int r = 0; r < 4; r++) l_run[r] = 1.f / l_run[r];
    #pragma unroll
    for (int dt = 0; dt < 8; dt++) {
        #pragma unroll
        for (int r = 0; r < 4; r++)
            rd[(size_t)(qrow0 + lg*4 + r)*MD + dt*16 + ll] = O[dt][r] * l_run[r];
    }
}

// ---------------- K3: fused GRU. Block tile 64 rows x 32 gate-cols ----------------
__global__ __launch_bounds__(256) void k_gru(const float* __restrict__ inp,
                                             const float* __restrict__ rd,
                                             const float* __restrict__ regs,
                                             const float* __restrict__ Wih,
                                             const float* __restrict__ bih,
                                             const float* __restrict__ Whh,
                                             const float* __restrict__ bhh,
                                             float* __restrict__ newregs)
{
    const int BK = 32;
    __shared__ float As[BK][64+1];
    __shared__ float Ws[3][BK][32+1];
    const int t = threadIdx.x;
    const int m0 = blockIdx.x * 64;
    const int n0 = blockIdx.y * 32;
    const int ty = t >> 4, tx = t & 15;
    float aR[4][2]={}, aZ[4][2]={}, aNi[4][2]={}, aNh[4][2]={};

    for (int k0 = 0; k0 < GRUIN; k0 += BK) {
        #pragma unroll
        for (int i = 0; i < 8; i++) {
            int l = t + i*256; int m = l >> 5, k = l & 31;
            int gk = k0 + k; int r = m0 + m;
            float v = (gk < INS) ? inp[(size_t)(r >> 10)*INS + gk]
                                 : rd[(size_t)r*MD + (gk - INS)];
            As[k][m] = v;
        }
        #pragma unroll
        for (int i = 0; i < 12; i++) {
            int l = t + i*256; int gg = l >> 10; int rem = l & 1023;
            int n = rem >> 5, k = rem & 31;
            Ws[gg][k][n] = Wih[(size_t)(gg*RS + n0 + n)*GRUIN + k0 + k];
        }
        __syncthreads();
        #pragma unroll
        for (int k = 0; k < BK; k++) {
            float a[4];
            #pragma unroll
            for (int i = 0; i < 4; i++) a[i] = As[k][ty*4+i];
            float bR[2], bZ[2], bN[2];
            #pragma unroll
            for (int j = 0; j < 2; j++) {
                bR[j]=Ws[0][k][tx*2+j]; bZ[j]=Ws[1][k][tx*2+j]; bN[j]=Ws[2][k][tx*2+j];
            }
            #pragma unroll
            for (int i = 0; i < 4; i++)
                #pragma unroll
                for (int j = 0; j < 2; j++) {
                    aR[i][j]  += a[i]*bR[j];
                    aZ[i][j]  += a[i]*bZ[j];
                    aNi[i][j] += a[i]*bN[j];
                }
        }
        __syncthreads();
    }
    for (int k0 = 0; k0 < RS; k0 += BK) {
        #pragma unroll
        for (int i = 0; i < 8; i++) {
            int l = t + i*256; int m = l >> 5, k = l & 31;
            As[k][m] = regs[(size_t)(m0+m)*RS + k0 + k];
        }
        #pragma unroll
        for (int i = 0; i < 12; i++) {
            int l = t + i*256; int gg = l >> 10; int rem = l & 1023;
            int n = rem >> 5, k = rem & 31;
            Ws[gg][k][n] = Whh[(size_t)(gg*RS + n0 + n)*RS + k0 + k];
        }
        __syncthreads();
        #pragma unroll
        for (int k = 0; k < BK; k++) {
            float a[4];
            #pragma unroll
            for (int i = 0; i < 4; i++) a[i] = As[k][ty*4+i];
            float bR[2], bZ[2], bN[2];
            #pragma unroll
            for (int j = 0; j < 2; j++) {
                bR[j]=Ws[0][k][tx*2+j]; bZ[j]=Ws[1][k][tx*2+j]; bN[j]=Ws[2][k][tx*2+j];
            }
            #pragma unroll
            for (int i = 0; i < 4; i++)
                #pragma unroll
                for (int j = 0; j < 2; j++) {
                    aR[i][j]  += a[i]*bR[j];
                    aZ[i][j]  += a[i]*bZ[j];
                    aNh[i][j] += a[i]*bN[j];
                }
        }
        __syncthreads();
    }
    #pragma unroll
    for (int i = 0; i < 4; i++) {
        int r = m0 + ty*4 + i;
        #pragma unroll
        for (int j = 0; j < 2; j++) {
            int o = n0 + tx*2 + j;
            float rr = sigf(aR[i][j] + bih[o]        + bhh[o]);
            float zz = sigf(aZ[i][j] + bih[o + RS]   + bhh[o + RS]);
            float nn = tanhf(aNi[i][j] + bih[o + 2*RS] + rr*(aNh[i][j] + bhh[o + 2*RS]));
            float cv = regs[(size_t)r*RS + o];
            newregs[(size_t)r*RS + o] = (1.f - zz)*nn + zz*cv;
        }
    }
}

// ---------------- K4: output GEMM  out0[16384,512] = newregs * Wout[512,256]^T + b ----------------
__global__ __launch_bounds__(256) void k_out(const float* __restrict__ A,
                                             const float* __restrict__ W,
                                             const float* __restrict__ bias,
                                             float* __restrict__ out0)
{
    const int BK = 32;
    __shared__ float As[BK][64+1];
    __shared__ float Ws[BK][64+1];
    const int t = threadIdx.x;
    const int m0 = blockIdx.x * 64;
    const int n0 = blockIdx.y * 64;
    const int ty = t >> 4, tx = t & 15;
    float acc[4][4] = {};
    for (int k0 = 0; k0 < RS; k0 += BK) {
        #pragma unroll
        for (int i = 0; i < 8; i++) {
            int l = t + i*256; int m = l >> 5, k = l & 31;
            As[k][m] = A[(size_t)(m0+m)*RS + k0 + k];
        }
        #pragma unroll
        for (int i = 0; i < 8; i++) {
            int l = t + i*256; int n = l >> 5, k = l & 31;
            Ws[k][n] = W[(size_t)(n0+n)*RS + k0 + k];
        }
        __syncthreads();
        #pragma unroll
        for (int k = 0; k < BK; k++) {
            float a[4], b[4];
            #pragma unroll
            for (int i = 0; i < 4; i++) a[i] = As[k][ty*4+i];
            #pragma unroll
            for (int j = 0; j < 4; j++) b[j] = Ws[k][tx*4+j];
            #pragma unroll
            for (int i = 0; i < 4; i++)
                #pragma unroll
                for (int j = 0; j < 4; j++) acc[i][j] += a[i]*b[j];
        }
        __syncthreads();
    }
    #pragma unroll
    for (int i = 0; i < 4; i++) {
        int r = m0 + ty*4 + i;
        #pragma unroll
        for (int j = 0; j < 4; j++) {
            int o = n0 + tx*4 + j;
            out0[(size_t)r*INS + o] = acc[i][j] + bias[o];
        }
    }
}

extern "C" void kernel_launch(void* const* d_in, const int* in_sizes, int n_in,
                              void* d_out, int out_size, void* d_ws, size_t ws_size,
                              hipStream_t stream)
{
    const float* inp  = (const float*)d_in[0];
    const float* regs = (const float*)d_in[1];
    const float* mem  = (const float*)d_in[2];
    const float* Wih  = (const float*)d_in[3];
    const float* bih  = (const float*)d_in[4];
    const float* Whh  = (const float*)d_in[5];
    const float* bhh  = (const float*)d_in[6];
    const float* Wmmu = (const float*)d_in[7];
    const float* bmmu = (const float*)d_in[8];
    const float* Wout = (const float*)d_in[9];
    const float* bout = (const float*)d_in[10];
    float* out = (float*)d_out;

    // ws layout (44 MB total):
    //   [0,4MB)   query bf16 (pre-scaled by 1/sqrt(128))
    //   [4,12MB)  read_data f32
    //   [12,28MB) memB bf16 row-major
    //   [28,44MB) memT bf16 transposed
    char* ws = (char*)d_ws;
    __hip_bfloat16* qbf  = (__hip_bfloat16*)ws;
    float*          rd   = (float*)(ws + ((size_t)4<<20));
    __hip_bfloat16* memB = (__hip_bfloat16*)(ws + ((size_t)12<<20));
    __hip_bfloat16* memT = (__hip_bfloat16*)(ws + ((size_t)28<<20));

    k_conv<<<B_*128, 256, 0, stream>>>(mem, memB, memT);
    dim3 g1(NROWS/64, (MMUO + 63)/64);
    k_mmu<<<g1, 256, 0, stream>>>(regs, Wmmu, bmmu, out, qbf);
    k_softmax3<<<NROWS/256, 256, 0, stream>>>(out);
    k_attn<<<B_*16, 256, 0, stream>>>(qbf, memB, memT, rd);
    dim3 g3(NROWS/64, RS/32);
    k_gru<<<g3, 256, 0, stream>>>(inp, rd, regs, Wih, bih, Whh, bhh, out + O_REGS);
    dim3 g4(NROWS/64, INS/64);
    k_out<<<g4, 256, 0, stream>>>(out + O_REGS, Wout, bout, out);
}

// Round 3
// 654.437 us; speedup vs baseline: 3.3912x; 2.1217x over previous
//
#include <hip/hip_runtime.h>
#include <hip/hip_bf16.h>
#include <math.h>

#define B_      16
#define NPUS    1024
#define MEMS    4096
#define INS     512
#define RS      256
#define MD      128
#define GRUIN   640
#define MMUO    644
#define NROWS   (B_*NPUS)   // 16384

// d_out flat offsets (reference return order)
#define O_OUT   0u
#define O_REGS  8388608u
#define O_WKEY  12582912u
#define O_WVAL  14680064u
#define O_WGATE 16777216u
#define O_SSDK  16793600u
#define O_SSDV  18890752u
#define O_SSDG  20987904u

typedef __attribute__((ext_vector_type(8))) short bf16x8;
typedef __attribute__((ext_vector_type(4))) float f32x4;
typedef __attribute__((ext_vector_type(4))) unsigned short u16x4;

__device__ __forceinline__ float sigf(float x){ return 1.f/(1.f+__expf(-x)); }
__device__ __forceinline__ unsigned short bfu(float x){
    __hip_bfloat16 h = __float2bfloat16(x);
    return __builtin_bit_cast(unsigned short, h);
}

// ---------------- K_cvt: fp32 -> bf16, vectorized x4 ----------------
__global__ __launch_bounds__(256) void k_cvt(const float* __restrict__ src,
                                             unsigned short* __restrict__ dst, int n4)
{
    int i = blockIdx.x*256 + threadIdx.x;
    if (i >= n4) return;
    float4 v = ((const float4*)src)[i];
    u16x4 o = { bfu(v.x), bfu(v.y), bfu(v.z), bfu(v.w) };
    ((u16x4*)dst)[i] = o;
}

// ---------------- K0: memory_context -> bf16 row-major + transposed ----------------
__global__ __launch_bounds__(256) void k_conv(const float* __restrict__ mem,
                                              __hip_bfloat16* __restrict__ memB,
                                              __hip_bfloat16* __restrict__ memT)
{
    __shared__ float Ms[32][129];
    const int t = threadIdx.x;
    const int b = blockIdx.x >> 7;
    const int m0 = (blockIdx.x & 127) << 5;
    const float* src = mem + ((size_t)b*MEMS + m0)*MD;
    for (int idx = t; idx < 32*128; idx += 256) {
        int m = idx >> 7, d = idx & 127;
        float v = src[(size_t)m*MD + d];
        Ms[m][d] = v;
        memB[((size_t)b*MEMS + m0 + m)*MD + d] = __float2bfloat16(v);
    }
    __syncthreads();
    for (int idx = t; idx < 128*32; idx += 256) {
        int d = idx >> 5, m = idx & 31;
        memT[((size_t)b*MD + d)*MEMS + m0 + m] = __float2bfloat16(Ms[m][d]);
    }
}

// ---------------- K1: MMU GEMM (MFMA)  C[16384,644] = regs * Wmmu^T + b ----------------
// 4 waves/block; wave: 16 rows x 256 cols. Grid (256, 3) with col guard at 644.
__global__ __launch_bounds__(256) void k_mmu(const __hip_bfloat16* __restrict__ Ab,
                                             const __hip_bfloat16* __restrict__ Wb,
                                             const float* __restrict__ bias,
                                             float* __restrict__ out,
                                             __hip_bfloat16* __restrict__ qbf)
{
    const int t = threadIdx.x, w = t >> 6, l = t & 63;
    const int lg = l >> 4, ll = l & 15;
    const int m0 = blockIdx.x*64 + w*16;
    const int n0 = blockIdx.y*256;
    const short* A = (const short*)Ab;
    const short* W = (const short*)Wb;
    f32x4 acc[16];
    #pragma unroll
    for (int c = 0; c < 16; c++) acc[c] = (f32x4){0,0,0,0};
    for (int k0 = 0; k0 < RS; k0 += 32) {
        bf16x8 af = *(const bf16x8*)(A + (size_t)(m0+ll)*RS + k0 + lg*8);
        #pragma unroll
        for (int c = 0; c < 16; c++) {
            int n = n0 + c*16 + ll;
            bf16x8 bf = {};
            if (n < MMUO) bf = *(const bf16x8*)(W + (size_t)n*RS + k0 + lg*8);
            acc[c] = __builtin_amdgcn_mfma_f32_16x16x32_bf16(af, bf, acc[c], 0, 0, 0);
        }
    }
    #pragma unroll
    for (int c = 0; c < 16; c++) {
        int o = n0 + c*16 + ll;
        if (o >= MMUO) continue;
        float bv = bias[o];
        #pragma unroll
        for (int r = 0; r < 4; r++) {
            int row = m0 + lg*4 + r;
            float v = acc[c][r] + bv;
            if      (o < MD)        qbf[(size_t)row*MD + o] = __float2bfloat16(v * 0.08838834764831845f);
            else if (o < 2*MD)      out[O_WKEY + (size_t)row*MD + (o -   MD)] = v;
            else if (o < 3*MD)      out[O_WVAL + (size_t)row*MD + (o - 2*MD)] = v;
            else if (o == 3*MD)     out[O_WGATE + row] = sigf(v);
            else if (o < 4*MD + 1)  out[O_SSDK + (size_t)row*MD + (o - (3*MD+1))] = v;
            else if (o < 5*MD + 1)  out[O_SSDV + (size_t)row*MD + (o - (4*MD+1))] = v;
            else                    out[O_SSDG + (size_t)row*3  + (o - (5*MD+1))] = v;
        }
    }
}

// ---------------- K1b: softmax over the 3 ssd_gate logits ----------------
__global__ void k_softmax3(float* __restrict__ out)
{
    int r = blockIdx.x*256 + threadIdx.x;
    if (r >= NROWS) return;
    float* p = out + O_SSDG + (size_t)r*3;
    float a = p[0], b = p[1], c = p[2];
    float m = fmaxf(a, fmaxf(b, c));
    float ea = __expf(a-m), eb = __expf(b-m), ec = __expf(c-m);
    float inv = 1.f/(ea+eb+ec);
    p[0] = ea*inv; p[1] = eb*inv; p[2] = ec*inv;
}

// ---------------- K2: MFMA flash attention -> rd (bf16) ----------------
__global__ __launch_bounds__(256) void k_attn(const __hip_bfloat16* __restrict__ qb,
                                              const __hip_bfloat16* __restrict__ memB,
                                              const __hip_bfloat16* __restrict__ memT,
                                              __hip_bfloat16* __restrict__ rdb)
{
    __shared__ __hip_bfloat16 Pl[4][16][40];
    const int t  = threadIdx.x;
    const int w  = t >> 6, l = t & 63;
    const int lg = l >> 4, ll = l & 15;
    const int b  = blockIdx.x >> 4;
    const int qt = blockIdx.x & 15;
    const int qrow0 = (b << 10) + (qt << 6) + (w << 4);

    bf16x8 qf[4];
    {
        const short* qp = (const short*)qb + (size_t)(qrow0 + ll)*MD;
        #pragma unroll
        for (int ks = 0; ks < 4; ks++)
            qf[ks] = *(const bf16x8*)(qp + ks*32 + lg*8);
    }
    f32x4 O[8];
    #pragma unroll
    for (int dt = 0; dt < 8; dt++) O[dt] = (f32x4){0.f,0.f,0.f,0.f};
    float m_run[4], l_run[4];
    #pragma unroll
    for (int r = 0; r < 4; r++) { m_run[r] = -INFINITY; l_run[r] = 0.f; }

    const short* Mb = (const short*)memB + (size_t)b*MEMS*MD;
    const short* Mt = (const short*)memT + (size_t)b*MD*MEMS;

    for (int k0 = 0; k0 < MEMS; k0 += 32) {
        f32x4 s0 = (f32x4){0,0,0,0}, s1 = (f32x4){0,0,0,0};
        #pragma unroll
        for (int ks = 0; ks < 4; ks++) {
            bf16x8 b0 = *(const bf16x8*)(Mb + (size_t)(k0      + ll)*MD + ks*32 + lg*8);
            bf16x8 b1 = *(const bf16x8*)(Mb + (size_t)(k0 + 16 + ll)*MD + ks*32 + lg*8);
            s0 = __builtin_amdgcn_mfma_f32_16x16x32_bf16(qf[ks], b0, s0, 0, 0, 0);
            s1 = __builtin_amdgcn_mfma_f32_16x16x32_bf16(qf[ks], b1, s1, 0, 0, 0);
        }
        float alpha[4];
        #pragma unroll
        for (int r = 0; r < 4; r++) {
            float v = fmaxf(s0[r], s1[r]);
            v = fmaxf(v, __shfl_xor(v, 1));
            v = fmaxf(v, __shfl_xor(v, 2));
            v = fmaxf(v, __shfl_xor(v, 4));
            v = fmaxf(v, __shfl_xor(v, 8));
            float mnew = fmaxf(m_run[r], v);
            alpha[r] = __expf(m_run[r] - mnew);
            m_run[r] = mnew;
            float p0 = __expf(s0[r] - mnew);
            float p1 = __expf(s1[r] - mnew);
            Pl[w][lg*4 + r][ll]      = __float2bfloat16(p0);
            Pl[w][lg*4 + r][16 + ll] = __float2bfloat16(p1);
            float p = p0 + p1;
            p += __shfl_xor(p, 1);
            p += __shfl_xor(p, 2);
            p += __shfl_xor(p, 4);
            p += __shfl_xor(p, 8);
            l_run[r] = l_run[r]*alpha[r] + p;
        }
        #pragma unroll
        for (int dt = 0; dt < 8; dt++) {
            #pragma unroll
            for (int r = 0; r < 4; r++) O[dt][r] *= alpha[r];
        }
        __builtin_amdgcn_wave_barrier();
        bf16x8 pa = *(const bf16x8*)(&Pl[w][ll][lg*8]);
        __builtin_amdgcn_wave_barrier();
        #pragma unroll
        for (int dt = 0; dt < 8; dt++) {
            bf16x8 vb = *(const bf16x8*)(Mt + (size_t)(dt*16 + ll)*MEMS + k0 + lg*8);
            O[dt] = __builtin_amdgcn_mfma_f32_16x16x32_bf16(pa, vb, O[dt], 0, 0, 0);
        }
    }
    #pragma unroll
    for (int r = 0; r < 4; r++) l_run[r] = 1.f / l_run[r];
    #pragma unroll
    for (int dt = 0; dt < 8; dt++) {
        #pragma unroll
        for (int r = 0; r < 4; r++)
            rdb[(size_t)(qrow0 + lg*4 + r)*MD + dt*16 + ll] = __float2bfloat16(O[dt][r] * l_run[r]);
    }
}

// ---------------- K3: fused GRU (MFMA) ----------------
// 4 waves/block (64 rows); wave: 16 rows x 64 gate-cols. Grid (256, 4).
// r,z accumulate gi+gh in one acc; n keeps gi_n / gh_n separate.
__global__ __launch_bounds__(256) void k_gru(const __hip_bfloat16* __restrict__ inpb,
                                             const __hip_bfloat16* __restrict__ rdb,
                                             const __hip_bfloat16* __restrict__ regsb,
                                             const float* __restrict__ regs,
                                             const __hip_bfloat16* __restrict__ Wihb,
                                             const float* __restrict__ bih,
                                             const __hip_bfloat16* __restrict__ Whhb,
                                             const float* __restrict__ bhh,
                                             float* __restrict__ newregs,
                                             __hip_bfloat16* __restrict__ nregsb)
{
    const int t = threadIdx.x, w = t >> 6, l = t & 63;
    const int lg = l >> 4, ll = l & 15;
    const int m0 = blockIdx.x*64 + w*16;
    const int n0 = blockIdx.y*64;
    const int batch = blockIdx.x >> 4;
    const short* Xi = (const short*)inpb + (size_t)batch*INS;
    const short* Rd = (const short*)rdb;
    const short* Hb = (const short*)regsb;
    const short* Wi = (const short*)Wihb;
    const short* Wh = (const short*)Whhb;

    f32x4 aR[4], aZ[4], aNi[4], aNh[4];
    #pragma unroll
    for (int c = 0; c < 4; c++) {
        aR[c] = (f32x4){0,0,0,0}; aZ[c] = (f32x4){0,0,0,0};
        aNi[c] = (f32x4){0,0,0,0}; aNh[c] = (f32x4){0,0,0,0};
    }
    // phase 1: gi = x . Wih^T, K=640 ; x = [inp(broadcast) | rd]
    for (int k0 = 0; k0 < GRUIN; k0 += 32) {
        bf16x8 af;
        if (k0 < INS) af = *(const bf16x8*)(Xi + k0 + lg*8);
        else          af = *(const bf16x8*)(Rd + (size_t)(m0+ll)*MD + (k0 - INS) + lg*8);
        #pragma unroll
        for (int c = 0; c < 4; c++) {
            int n = n0 + c*16 + ll;
            bf16x8 bR = *(const bf16x8*)(Wi + (size_t)(n         )*GRUIN + k0 + lg*8);
            bf16x8 bZ = *(const bf16x8*)(Wi + (size_t)(n +   RS  )*GRUIN + k0 + lg*8);
            bf16x8 bN = *(const bf16x8*)(Wi + (size_t)(n + 2*RS  )*GRUIN + k0 + lg*8);
            aR[c]  = __builtin_amdgcn_mfma_f32_16x16x32_bf16(af, bR, aR[c],  0, 0, 0);
            aZ[c]  = __builtin_amdgcn_mfma_f32_16x16x32_bf16(af, bZ, aZ[c],  0, 0, 0);
            aNi[c] = __builtin_amdgcn_mfma_f32_16x16x32_bf16(af, bN, aNi[c], 0, 0, 0);
        }
    }
    // phase 2: gh = h . Whh^T, K=256
    for (int k0 = 0; k0 < RS; k0 += 32) {
        bf16x8 af = *(const bf16x8*)(Hb + (size_t)(m0+ll)*RS + k0 + lg*8);
        #pragma unroll
        for (int c = 0; c < 4; c++) {
            int n = n0 + c*16 + ll;
            bf16x8 bR = *(const bf16x8*)(Wh + (size_t)(n        )*RS + k0 + lg*8);
            bf16x8 bZ = *(const bf16x8*)(Wh + (size_t)(n +   RS )*RS + k0 + lg*8);
            bf16x8 bN = *(const bf16x8*)(Wh + (size_t)(n + 2*RS )*RS + k0 + lg*8);
            aR[c]  = __builtin_amdgcn_mfma_f32_16x16x32_bf16(af, bR, aR[c],  0, 0, 0);
            aZ[c]  = __builtin_amdgcn_mfma_f32_16x16x32_bf16(af, bZ, aZ[c],  0, 0, 0);
            aNh[c] = __builtin_amdgcn_mfma_f32_16x16x32_bf16(af, bN, aNh[c], 0, 0, 0);
        }
    }
    // epilogue
    #pragma unroll
    for (int c = 0; c < 4; c++) {
        int o = n0 + c*16 + ll;
        float bR = bih[o]        + bhh[o];
        float bZ = bih[o +   RS] + bhh[o +   RS];
        float bNi = bih[o + 2*RS];
        float bNh = bhh[o + 2*RS];
        #pragma unroll
        for (int r = 0; r < 4; r++) {
            int row = m0 + lg*4 + r;
            float rr = sigf(aR[c][r] + bR);
            float zz = sigf(aZ[c][r] + bZ);
            float nn = tanhf(aNi[c][r] + bNi + rr*(aNh[c][r] + bNh));
            float cv = regs[(size_t)row*RS + o];
            float nv = (1.f - zz)*nn + zz*cv;
            newregs[(size_t)row*RS + o] = nv;
            nregsb[(size_t)row*RS + o] = __float2bfloat16(nv);
        }
    }
}

// ---------------- K4: output GEMM (MFMA)  out0[16384,512] = newregs * Wout^T + b ----------------
// 4 waves/block; wave: 16 rows x 256 cols. Grid (256, 2).
__global__ __launch_bounds__(256) void k_out(const __hip_bfloat16* __restrict__ Ab,
                                             const __hip_bfloat16* __restrict__ Wb,
                                             const float* __restrict__ bias,
                                             float* __restrict__ out0)
{
    const int t = threadIdx.x, w = t >> 6, l = t & 63;
    const int lg = l >> 4, ll = l & 15;
    const int m0 = blockIdx.x*64 + w*16;
    const int n0 = blockIdx.y*256;
    const short* A = (const short*)Ab;
    const short* W = (const short*)Wb;
    f32x4 acc[16];
    #pragma unroll
    for (int c = 0; c < 16; c++) acc[c] = (f32x4){0,0,0,0};
    for (int k0 = 0; k0 < RS; k0 += 32) {
        bf16x8 af = *(const bf16x8*)(A + (size_t)(m0+ll)*RS + k0 + lg*8);
        #pragma unroll
        for (int c = 0; c < 16; c++) {
            int n = n0 + c*16 + ll;
            bf16x8 bf = *(const bf16x8*)(W + (size_t)n*RS + k0 + lg*8);
            acc[c] = __builtin_amdgcn_mfma_f32_16x16x32_bf16(af, bf, acc[c], 0, 0, 0);
        }
    }
    #pragma unroll
    for (int c = 0; c < 16; c++) {
        int o = n0 + c*16 + ll;
        float bv = bias[o];
        #pragma unroll
        for (int r = 0; r < 4; r++) {
            int row = m0 + lg*4 + r;
            out0[(size_t)row*INS + o] = acc[c][r] + bv;
        }
    }
}

extern "C" void kernel_launch(void* const* d_in, const int* in_sizes, int n_in,
                              void* d_out, int out_size, void* d_ws, size_t ws_size,
                              hipStream_t stream)
{
    const float* inp  = (const float*)d_in[0];
    const float* regs = (const float*)d_in[1];
    const float* mem  = (const float*)d_in[2];
    const float* Wih  = (const float*)d_in[3];
    const float* bih  = (const float*)d_in[4];
    const float* Whh  = (const float*)d_in[5];
    const float* bhh  = (const float*)d_in[6];
    const float* Wmmu = (const float*)d_in[7];
    const float* bmmu = (const float*)d_in[8];
    const float* Wout = (const float*)d_in[9];
    const float* bout = (const float*)d_in[10];
    float* out = (float*)d_out;

    // ws layout:
    //   [0,4MB)    qbf bf16 (pre-scaled)
    //   [4,8MB)    rd bf16
    //   [8,24MB)   memB bf16
    //   [24,40MB)  memT bf16
    //   [40,48MB)  regs bf16
    //   [48,56MB)  nregs bf16
    //   [56MB..)   weights bf16: Wmmu, Wih, Whh, Wout, inp
    char* ws = (char*)d_ws;
    __hip_bfloat16* qbf    = (__hip_bfloat16*)(ws);
    __hip_bfloat16* rdb    = (__hip_bfloat16*)(ws + ((size_t)4<<20));
    __hip_bfloat16* memB   = (__hip_bfloat16*)(ws + ((size_t)8<<20));
    __hip_bfloat16* memT   = (__hip_bfloat16*)(ws + ((size_t)24<<20));
    __hip_bfloat16* regsb  = (__hip_bfloat16*)(ws + ((size_t)40<<20));
    __hip_bfloat16* nregsb = (__hip_bfloat16*)(ws + ((size_t)48<<20));
    __hip_bfloat16* Wmmub  = (__hip_bfloat16*)(ws + ((size_t)56<<20));                 // 164864*2B
    __hip_bfloat16* Wihb   = (__hip_bfloat16*)(ws + ((size_t)56<<20) + ( 1<<20));      // 491520*2B
    __hip_bfloat16* Whhb   = (__hip_bfloat16*)(ws + ((size_t)56<<20) + ( 2<<20));      // 196608*2B
    __hip_bfloat16* Woutb  = (__hip_bfloat16*)(ws + ((size_t)56<<20) + ( 3<<20));      // 131072*2B
    __hip_bfloat16* inpb   = (__hip_bfloat16*)(ws + ((size_t)56<<20) + ( 4<<20));      // 8192*2B

    k_cvt<<<(164864/4 + 255)/256, 256, 0, stream>>>(Wmmu, (unsigned short*)Wmmub, 164864/4);
    k_cvt<<<(491520/4 + 255)/256, 256, 0, stream>>>(Wih,  (unsigned short*)Wihb,  491520/4);
    k_cvt<<<(196608/4 + 255)/256, 256, 0, stream>>>(Whh,  (unsigned short*)Whhb,  196608/4);
    k_cvt<<<(131072/4 + 255)/256, 256, 0, stream>>>(Wout, (unsigned short*)Woutb, 131072/4);
    k_cvt<<<(8192/4   + 255)/256, 256, 0, stream>>>(inp,  (unsigned short*)inpb,  8192/4);
    k_cvt<<<(4194304/4+ 255)/256, 256, 0, stream>>>(regs, (unsigned short*)regsb, 4194304/4);
    k_conv<<<B_*128, 256, 0, stream>>>(mem, memB, memT);

    dim3 g1(NROWS/64, 3);
    k_mmu<<<g1, 256, 0, stream>>>(regsb, Wmmub, bmmu, out, qbf);
    k_softmax3<<<NROWS/256, 256, 0, stream>>>(out);
    k_attn<<<B_*16, 256, 0, stream>>>(qbf, memB, memT, rdb);
    dim3 g3(NROWS/64, 4);
    k_gru<<<g3, 256, 0, stream>>>(inpb, rdb, regsb, regs, Wihb, bih, Whhb, bhh,
                                  out + O_REGS, nregsb);
    dim3 g4(NROWS/64, 2);
    k_out<<<g4, 256, 0, stream>>>(nregsb, Woutb, bout, out);
}

// Round 4
// 530.094 us; speedup vs baseline: 4.1867x; 1.2346x over previous
//
#include <hip/hip_runtime.h>
#include <hip/hip_bf16.h>
#include <math.h>

#define B_      16
#define NPUS    1024
#define MEMS    4096
#define INS     512
#define RS      256
#define MD      128
#define GRUIN   640
#define MMUO    644
#define NROWS   (B_*NPUS)   // 16384

// d_out flat offsets (reference return order)
#define O_OUT   0u
#define O_REGS  8388608u
#define O_WKEY  12582912u
#define O_WVAL  14680064u
#define O_WGATE 16777216u
#define O_SSDK  16793600u
#define O_SSDV  18890752u
#define O_SSDG  20987904u

typedef __attribute__((ext_vector_type(8))) short bf16x8;
typedef __attribute__((ext_vector_type(4))) float f32x4;
typedef __attribute__((ext_vector_type(4))) unsigned short u16x4;

__device__ __forceinline__ float sigf(float x){ return 1.f/(1.f+__expf(-x)); }
__device__ __forceinline__ unsigned short bfu(float x){
    __hip_bfloat16 h = __float2bfloat16(x);
    return __builtin_bit_cast(unsigned short, h);
}

// ---------------- K_cvt: fp32 -> bf16, vectorized x4 ----------------
__global__ __launch_bounds__(256) void k_cvt(const float* __restrict__ src,
                                             unsigned short* __restrict__ dst, int n4)
{
    int i = blockIdx.x*256 + threadIdx.x;
    if (i >= n4) return;
    float4 v = ((const float4*)src)[i];
    u16x4 o = { bfu(v.x), bfu(v.y), bfu(v.z), bfu(v.w) };
    ((u16x4*)dst)[i] = o;
}

// ---------------- K0: memory_context -> bf16 row-major + transposed ----------------
__global__ __launch_bounds__(256) void k_conv(const float* __restrict__ mem,
                                              __hip_bfloat16* __restrict__ memB,
                                              __hip_bfloat16* __restrict__ memT)
{
    __shared__ float Ms[32][129];
    const int t = threadIdx.x;
    const int b = blockIdx.x >> 7;
    const int m0 = (blockIdx.x & 127) << 5;
    const float* src = mem + ((size_t)b*MEMS + m0)*MD;
    for (int idx = t; idx < 32*128; idx += 256) {
        int m = idx >> 7, d = idx & 127;
        float v = src[(size_t)m*MD + d];
        Ms[m][d] = v;
        memB[((size_t)b*MEMS + m0 + m)*MD + d] = __float2bfloat16(v);
    }
    __syncthreads();
    for (int idx = t; idx < 128*32; idx += 256) {
        int d = idx >> 5, m = idx & 31;
        memT[((size_t)b*MD + d)*MEMS + m0 + m] = __float2bfloat16(Ms[m][d]);
    }
}

// ---------------- K1: MMU GEMM (MFMA)  C[16384,644] = regs * Wmmu^T + b ----------------
__global__ __launch_bounds__(256) void k_mmu(const __hip_bfloat16* __restrict__ Ab,
                                             const __hip_bfloat16* __restrict__ Wb,
                                             const float* __restrict__ bias,
                                             float* __restrict__ out,
                                             __hip_bfloat16* __restrict__ qbf)
{
    const int t = threadIdx.x, w = t >> 6, l = t & 63;
    const int lg = l >> 4, ll = l & 15;
    const int m0 = blockIdx.x*64 + w*16;
    const int n0 = blockIdx.y*256;
    const short* A = (const short*)Ab;
    const short* W = (const short*)Wb;
    f32x4 acc[16];
    #pragma unroll
    for (int c = 0; c < 16; c++) acc[c] = (f32x4){0,0,0,0};
    for (int k0 = 0; k0 < RS; k0 += 32) {
        bf16x8 af = *(const bf16x8*)(A + (size_t)(m0+ll)*RS + k0 + lg*8);
        #pragma unroll
        for (int c = 0; c < 16; c++) {
            int n = n0 + c*16 + ll;
            bf16x8 bf = {};
            if (n < MMUO) bf = *(const bf16x8*)(W + (size_t)n*RS + k0 + lg*8);
            acc[c] = __builtin_amdgcn_mfma_f32_16x16x32_bf16(af, bf, acc[c], 0, 0, 0);
        }
    }
    #pragma unroll
    for (int c = 0; c < 16; c++) {
        int o = n0 + c*16 + ll;
        if (o >= MMUO) continue;
        float bv = bias[o];
        #pragma unroll
        for (int r = 0; r < 4; r++) {
            int row = m0 + lg*4 + r;
            float v = acc[c][r] + bv;
            if      (o < MD)        qbf[(size_t)row*MD + o] = __float2bfloat16(v * 0.08838834764831845f);
            else if (o < 2*MD)      out[O_WKEY + (size_t)row*MD + (o -   MD)] = v;
            else if (o < 3*MD)      out[O_WVAL + (size_t)row*MD + (o - 2*MD)] = v;
            else if (o == 3*MD)     out[O_WGATE + row] = sigf(v);
            else if (o < 4*MD + 1)  out[O_SSDK + (size_t)row*MD + (o - (3*MD+1))] = v;
            else if (o < 5*MD + 1)  out[O_SSDV + (size_t)row*MD + (o - (4*MD+1))] = v;
            else                    out[O_SSDG + (size_t)row*3  + (o - (5*MD+1))] = v;
        }
    }
}

// ---------------- K1b: softmax over the 3 ssd_gate logits ----------------
__global__ void k_softmax3(float* __restrict__ out)
{
    int r = blockIdx.x*256 + threadIdx.x;
    if (r >= NROWS) return;
    float* p = out + O_SSDG + (size_t)r*3;
    float a = p[0], b = p[1], c = p[2];
    float m = fmaxf(a, fmaxf(b, c));
    float ea = __expf(a-m), eb = __expf(b-m), ec = __expf(c-m);
    float inv = 1.f/(ea+eb+ec);
    p[0] = ea*inv; p[1] = eb*inv; p[2] = ec*inv;
}

// ---------------- K2: split-K MFMA flash attention -> rd (bf16) ----------------
// 1024 blocks x 4 waves. Block owns 16 q-rows; wave w processes keys [w*1024,(w+1)*1024)
// with private online-softmax state; block-level combine in LDS merges the 4 partials.
// XCD swizzle: batch b -> XCD b&7, so each XCD's L2 holds exactly 2 batches (4MB).
__global__ __launch_bounds__(256) void k_attn(const __hip_bfloat16* __restrict__ qb,
                                              const __hip_bfloat16* __restrict__ memB,
                                              const __hip_bfloat16* __restrict__ memT,
                                              __hip_bfloat16* __restrict__ rdb)
{
    __shared__ float Ow[4][16][132];           // +4 pad: conflict-free combine reads
    __shared__ float Ml[4][16], Ll[4][16];
    __shared__ __hip_bfloat16 Pl[4][16][40];
    const int t  = threadIdx.x;
    const int w  = t >> 6, l = t & 63;
    const int lg = l >> 4, ll = l & 15;
    // swizzle: dispatch id -> (batch, q-block) with batch pinned to XCD (id & 7)
    const int bid  = blockIdx.x;
    const int xcd  = bid & 7, rest = bid >> 3;
    const int b    = xcd + ((rest >> 6) << 3);    // 0..15
    const int qblk = rest & 63;                   // 0..63
    const int qrow0 = (b << 10) + (qblk << 4);

    // Q A-fragments (same 16 rows for all 4 waves -> L1 broadcast)
    bf16x8 qf[4];
    {
        const short* qp = (const short*)qb + (size_t)(qrow0 + ll)*MD;
        #pragma unroll
        for (int ks = 0; ks < 4; ks++)
            qf[ks] = *(const bf16x8*)(qp + ks*32 + lg*8);
    }
    f32x4 O[8];
    #pragma unroll
    for (int dt = 0; dt < 8; dt++) O[dt] = (f32x4){0.f,0.f,0.f,0.f};
    float m_run[4], l_run[4];
    #pragma unroll
    for (int r = 0; r < 4; r++) { m_run[r] = -INFINITY; l_run[r] = 0.f; }

    const short* Mb = (const short*)memB + (size_t)b*MEMS*MD;
    const short* Mt = (const short*)memT + (size_t)b*MD*MEMS;
    const int k_beg = w << 10, k_end = k_beg + 1024;

    for (int k0 = k_beg; k0 < k_end; k0 += 32) {
        // V fragments first: independent of QK/softmax -> overlaps their latency
        bf16x8 vb[8];
        #pragma unroll
        for (int dt = 0; dt < 8; dt++)
            vb[dt] = *(const bf16x8*)(Mt + (size_t)(dt*16 + ll)*MEMS + k0 + lg*8);
        // QK^T
        f32x4 s0 = (f32x4){0,0,0,0}, s1 = (f32x4){0,0,0,0};
        #pragma unroll
        for (int ks = 0; ks < 4; ks++) {
            bf16x8 b0 = *(const bf16x8*)(Mb + (size_t)(k0      + ll)*MD + ks*32 + lg*8);
            bf16x8 b1 = *(const bf16x8*)(Mb + (size_t)(k0 + 16 + ll)*MD + ks*32 + lg*8);
            s0 = __builtin_amdgcn_mfma_f32_16x16x32_bf16(qf[ks], b0, s0, 0, 0, 0);
            s1 = __builtin_amdgcn_mfma_f32_16x16x32_bf16(qf[ks], b1, s1, 0, 0, 0);
        }
        // online softmax (C layout: col=ll=key, row=lg*4+r=query)
        float alpha[4];
        #pragma unroll
        for (int r = 0; r < 4; r++) {
            float v = fmaxf(s0[r], s1[r]);
            v = fmaxf(v, __shfl_xor(v, 1));
            v = fmaxf(v, __shfl_xor(v, 2));
            v = fmaxf(v, __shfl_xor(v, 4));
            v = fmaxf(v, __shfl_xor(v, 8));
            float mnew = fmaxf(m_run[r], v);
            alpha[r] = __expf(m_run[r] - mnew);
            m_run[r] = mnew;
            float p0 = __expf(s0[r] - mnew);
            float p1 = __expf(s1[r] - mnew);
            Pl[w][lg*4 + r][ll]      = __float2bfloat16(p0);
            Pl[w][lg*4 + r][16 + ll] = __float2bfloat16(p1);
            float p = p0 + p1;
            p += __shfl_xor(p, 1);
            p += __shfl_xor(p, 2);
            p += __shfl_xor(p, 4);
            p += __shfl_xor(p, 8);
            l_run[r] = l_run[r]*alpha[r] + p;
        }
        #pragma unroll
        for (int dt = 0; dt < 8; dt++) {
            #pragma unroll
            for (int r = 0; r < 4; r++) O[dt][r] *= alpha[r];
        }
        __builtin_amdgcn_wave_barrier();
        bf16x8 pa = *(const bf16x8*)(&Pl[w][ll][lg*8]);
        __builtin_amdgcn_wave_barrier();
        #pragma unroll
        for (int dt = 0; dt < 8; dt++)
            O[dt] = __builtin_amdgcn_mfma_f32_16x16x32_bf16(pa, vb[dt], O[dt], 0, 0, 0);
    }
    // dump partials
    #pragma unroll
    for (int dt = 0; dt < 8; dt++)
        #pragma unroll
        for (int r = 0; r < 4; r++)
            Ow[w][lg*4 + r][dt*16 + ll] = O[dt][r];
    if (ll == 0) {
        #pragma unroll
        for (int r = 0; r < 4; r++) { Ml[w][lg*4 + r] = m_run[r]; Ll[w][lg*4 + r] = l_run[r]; }
    }
    __syncthreads();
    // combine: thread -> (row tr, 8 cols at tc0)
    const int tr = t >> 4, tc0 = (t & 15) * 8;
    float m0v = Ml[0][tr], m1v = Ml[1][tr], m2v = Ml[2][tr], m3v = Ml[3][tr];
    float M = fmaxf(fmaxf(m0v, m1v), fmaxf(m2v, m3v));
    float w0 = __expf(m0v - M), w1 = __expf(m1v - M), w2 = __expf(m2v - M), w3 = __expf(m3v - M);
    float L = w0*Ll[0][tr] + w1*Ll[1][tr] + w2*Ll[2][tr] + w3*Ll[3][tr];
    float invL = 1.f / L;
    #pragma unroll
    for (int j = 0; j < 8; j++) {
        int c = tc0 + j;
        float o = w0*Ow[0][tr][c] + w1*Ow[1][tr][c] + w2*Ow[2][tr][c] + w3*Ow[3][tr][c];
        rdb[(size_t)(qrow0 + tr)*MD + c] = __float2bfloat16(o * invL);
    }
}

// ---------------- K3: fused GRU (MFMA) ----------------
__global__ __launch_bounds__(256) void k_gru(const __hip_bfloat16* __restrict__ inpb,
                                             const __hip_bfloat16* __restrict__ rdb,
                                             const __hip_bfloat16* __restrict__ regsb,
                                             const float* __restrict__ regs,
                                             const __hip_bfloat16* __restrict__ Wihb,
                                             const float* __restrict__ bih,
                                             const __hip_bfloat16* __restrict__ Whhb,
                                             const float* __restrict__ bhh,
                                             float* __restrict__ newregs,
                                             __hip_bfloat16* __restrict__ nregsb)
{
    const int t = threadIdx.x, w = t >> 6, l = t & 63;
    const int lg = l >> 4, ll = l & 15;
    const int m0 = blockIdx.x*64 + w*16;
    const int n0 = blockIdx.y*64;
    const int batch = blockIdx.x >> 4;
    const short* Xi = (const short*)inpb + (size_t)batch*INS;
    const short* Rd = (const short*)rdb;
    const short* Hb = (const short*)regsb;
    const short* Wi = (const short*)Wihb;
    const short* Wh = (const short*)Whhb;

    f32x4 aR[4], aZ[4], aNi[4], aNh[4];
    #pragma unroll
    for (int c = 0; c < 4; c++) {
        aR[c] = (f32x4){0,0,0,0}; aZ[c] = (f32x4){0,0,0,0};
        aNi[c] = (f32x4){0,0,0,0}; aNh[c] = (f32x4){0,0,0,0};
    }
    for (int k0 = 0; k0 < GRUIN; k0 += 32) {
        bf16x8 af;
        if (k0 < INS) af = *(const bf16x8*)(Xi + k0 + lg*8);
        else          af = *(const bf16x8*)(Rd + (size_t)(m0+ll)*MD + (k0 - INS) + lg*8);
        #pragma unroll
        for (int c = 0; c < 4; c++) {
            int n = n0 + c*16 + ll;
            bf16x8 bR = *(const bf16x8*)(Wi + (size_t)(n         )*GRUIN + k0 + lg*8);
            bf16x8 bZ = *(const bf16x8*)(Wi + (size_t)(n +   RS  )*GRUIN + k0 + lg*8);
            bf16x8 bN = *(const bf16x8*)(Wi + (size_t)(n + 2*RS  )*GRUIN + k0 + lg*8);
            aR[c]  = __builtin_amdgcn_mfma_f32_16x16x32_bf16(af, bR, aR[c],  0, 0, 0);
            aZ[c]  = __builtin_amdgcn_mfma_f32_16x16x32_bf16(af, bZ, aZ[c],  0, 0, 0);
            aNi[c] = __builtin_amdgcn_mfma_f32_16x16x32_bf16(af, bN, aNi[c], 0, 0, 0);
        }
    }
    for (int k0 = 0; k0 < RS; k0 += 32) {
        bf16x8 af = *(const bf16x8*)(Hb + (size_t)(m0+ll)*RS + k0 + lg*8);
        #pragma unroll
        for (int c = 0; c < 4; c++) {
            int n = n0 + c*16 + ll;
            bf16x8 bR = *(const bf16x8*)(Wh + (size_t)(n        )*RS + k0 + lg*8);
            bf16x8 bZ = *(const bf16x8*)(Wh + (size_t)(n +   RS )*RS + k0 + lg*8);
            bf16x8 bN = *(const bf16x8*)(Wh + (size_t)(n + 2*RS )*RS + k0 + lg*8);
            aR[c]  = __builtin_amdgcn_mfma_f32_16x16x32_bf16(af, bR, aR[c],  0, 0, 0);
            aZ[c]  = __builtin_amdgcn_mfma_f32_16x16x32_bf16(af, bZ, aZ[c],  0, 0, 0);
            aNh[c] = __builtin_amdgcn_mfma_f32_16x16x32_bf16(af, bN, aNh[c], 0, 0, 0);
        }
    }
    #pragma unroll
    for (int c = 0; c < 4; c++) {
        int o = n0 + c*16 + ll;
        float bR = bih[o]        + bhh[o];
        float bZ = bih[o +   RS] + bhh[o +   RS];
        float bNi = bih[o + 2*RS];
        float bNh = bhh[o + 2*RS];
        #pragma unroll
        for (int r = 0; r < 4; r++) {
            int row = m0 + lg*4 + r;
            float rr = sigf(aR[c][r] + bR);
            float zz = sigf(aZ[c][r] + bZ);
            float nn = tanhf(aNi[c][r] + bNi + rr*(aNh[c][r] + bNh));
            float cv = regs[(size_t)row*RS + o];
            float nv = (1.f - zz)*nn + zz*cv;
            newregs[(size_t)row*RS + o] = nv;
            nregsb[(size_t)row*RS + o] = __float2bfloat16(nv);
        }
    }
}

// ---------------- K4: output GEMM (MFMA) ----------------
__global__ __launch_bounds__(256) void k_out(const __hip_bfloat16* __restrict__ Ab,
                                             const __hip_bfloat16* __restrict__ Wb,
                                             const float* __restrict__ bias,
                                             float* __restrict__ out0)
{
    const int t = threadIdx.x, w = t >> 6, l = t & 63;
    const int lg = l >> 4, ll = l & 15;
    const int m0 = blockIdx.x*64 + w*16;
    const int n0 = blockIdx.y*256;
    const short* A = (const short*)Ab;
    const short* W = (const short*)Wb;
    f32x4 acc[16];
    #pragma unroll
    for (int c = 0; c < 16; c++) acc[c] = (f32x4){0,0,0,0};
    for (int k0 = 0; k0 < RS; k0 += 32) {
        bf16x8 af = *(const bf16x8*)(A + (size_t)(m0+ll)*RS + k0 + lg*8);
        #pragma unroll
        for (int c = 0; c < 16; c++) {
            int n = n0 + c*16 + ll;
            bf16x8 bf = *(const bf16x8*)(W + (size_t)n*RS + k0 + lg*8);
            acc[c] = __builtin_amdgcn_mfma_f32_16x16x32_bf16(af, bf, acc[c], 0, 0, 0);
        }
    }
    #pragma unroll
    for (int c = 0; c < 16; c++) {
        int o = n0 + c*16 + ll;
        float bv = bias[o];
        #pragma unroll
        for (int r = 0; r < 4; r++) {
            int row = m0 + lg*4 + r;
            out0[(size_t)row*INS + o] = acc[c][r] + bv;
        }
    }
}

extern "C" void kernel_launch(void* const* d_in, const int* in_sizes, int n_in,
                              void* d_out, int out_size, void* d_ws, size_t ws_size,
                              hipStream_t stream)
{
    const float* inp  = (const float*)d_in[0];
    const float* regs = (const float*)d_in[1];
    const float* mem  = (const float*)d_in[2];
    const float* Wih  = (const float*)d_in[3];
    const float* bih  = (const float*)d_in[4];
    const float* Whh  = (const float*)d_in[5];
    const float* bhh  = (const float*)d_in[6];
    const float* Wmmu = (const float*)d_in[7];
    const float* bmmu = (const float*)d_in[8];
    const float* Wout = (const float*)d_in[9];
    const float* bout = (const float*)d_in[10];
    float* out = (float*)d_out;

    char* ws = (char*)d_ws;
    __hip_bfloat16* qbf    = (__hip_bfloat16*)(ws);
    __hip_bfloat16* rdb    = (__hip_bfloat16*)(ws + ((size_t)4<<20));
    __hip_bfloat16* memB   = (__hip_bfloat16*)(ws + ((size_t)8<<20));
    __hip_bfloat16* memT   = (__hip_bfloat16*)(ws + ((size_t)24<<20));
    __hip_bfloat16* regsb  = (__hip_bfloat16*)(ws + ((size_t)40<<20));
    __hip_bfloat16* nregsb = (__hip_bfloat16*)(ws + ((size_t)48<<20));
    __hip_bfloat16* Wmmub  = (__hip_bfloat16*)(ws + ((size_t)56<<20));
    __hip_bfloat16* Wihb   = (__hip_bfloat16*)(ws + ((size_t)56<<20) + ( 1<<20));
    __hip_bfloat16* Whhb   = (__hip_bfloat16*)(ws + ((size_t)56<<20) + ( 2<<20));
    __hip_bfloat16* Woutb  = (__hip_bfloat16*)(ws + ((size_t)56<<20) + ( 3<<20));
    __hip_bfloat16* inpb   = (__hip_bfloat16*)(ws + ((size_t)56<<20) + ( 4<<20));

    k_cvt<<<(164864/4 + 255)/256, 256, 0, stream>>>(Wmmu, (unsigned short*)Wmmub, 164864/4);
    k_cvt<<<(491520/4 + 255)/256, 256, 0, stream>>>(Wih,  (unsigned short*)Wihb,  491520/4);
    k_cvt<<<(196608/4 + 255)/256, 256, 0, stream>>>(Whh,  (unsigned short*)Whhb,  196608/4);
    k_cvt<<<(131072/4 + 255)/256, 256, 0, stream>>>(Wout, (unsigned short*)Woutb, 131072/4);
    k_cvt<<<(8192/4   + 255)/256, 256, 0, stream>>>(inp,  (unsigned short*)inpb,  8192/4);
    k_cvt<<<(4194304/4+ 255)/256, 256, 0, stream>>>(regs, (unsigned short*)regsb, 4194304/4);
    k_conv<<<B_*128, 256, 0, stream>>>(mem, memB, memT);

    dim3 g1(NROWS/64, 3);
    k_mmu<<<g1, 256, 0, stream>>>(regsb, Wmmub, bmmu, out, qbf);
    k_softmax3<<<NROWS/256, 256, 0, stream>>>(out);
    k_attn<<<NROWS/16, 256, 0, stream>>>(qbf, memB, memT, rdb);
    dim3 g3(NROWS/64, 4);
    k_gru<<<g3, 256, 0, stream>>>(inpb, rdb, regsb, regs, Wihb, bih, Whhb, bhh,
                                  out + O_REGS, nregsb);
    dim3 g4(NROWS/64, 2);
    k_out<<<g4, 256, 0, stream>>>(nregsb, Woutb, bout, out);
}